// Round 6
// baseline (232.363 us; speedup 1.0000x reference)
//
#include <hip/hip_runtime.h>
#include <hip/hip_bf16.h>

typedef __hip_bfloat16 bf16;
typedef __attribute__((ext_vector_type(8))) short short8;
typedef __attribute__((ext_vector_type(4))) float floatx4;

#define AS1 __attribute__((address_space(1)))
#define AS3 __attribute__((address_space(3)))

#define K_DIM 1024
#define LN_TAU_STEP 1.15129254649702295f

// ---------------- transpose f32 [K][4096] -> bf16 [perm(n)][K], z selects Wr/Ws ----------------
// physical row p(n): u=n>>3, m=n&7 -> p = (u>>5)*256 + (m>>2)*128 + ((u>>3)&3)*32 + ((m>>1)&1)*16
//                                        + (m&1)*8 + (u&7)
__global__ void transpose_rs(const float* __restrict__ Wr, const float* __restrict__ Ws,
                             bf16* __restrict__ dst) {
  __shared__ float tile[32][33];
  const float* src = blockIdx.z ? Ws : Wr;
  bf16* d = dst + (size_t)blockIdx.z * 4096 * 1024;
  int n0 = blockIdx.x * 32, k0 = blockIdx.y * 32;
  int tx = threadIdx.x, ty = threadIdx.y;
#pragma unroll
  for (int i = 0; i < 32; i += 8)
    tile[ty + i][tx] = src[(size_t)(k0 + ty + i) * 4096 + n0 + tx];
  __syncthreads();
#pragma unroll
  for (int i = 0; i < 32; i += 8) {
    int n = n0 + ty + i;
    int u = n >> 3, m = n & 7;
    int p = (u >> 5) * 256 + (m >> 2) * 128 + ((u >> 3) & 3) * 32 + ((m >> 1) & 1) * 16 +
            (m & 1) * 8 + (u & 7);
    d[(size_t)p * 1024 + k0 + tx] = __float2bfloat16(tile[tx][ty + i]);
  }
}

// ---------------- transpose f32 [1024][512] -> bf16 [512][1024] (natural) ----------------
__global__ void transpose_q(const float* __restrict__ src, bf16* __restrict__ dst) {
  __shared__ float tile[32][33];
  int n0 = blockIdx.x * 32, k0 = blockIdx.y * 32;
  int tx = threadIdx.x, ty = threadIdx.y;
#pragma unroll
  for (int i = 0; i < 32; i += 8)
    tile[ty + i][tx] = src[(size_t)(k0 + ty + i) * 512 + n0 + tx];
  __syncthreads();
#pragma unroll
  for (int i = 0; i < 32; i += 8)
    dst[(size_t)(n0 + ty + i) * 1024 + k0 + tx] = __float2bfloat16(tile[tx][ty + i]);
}

// ---------------- build fused = [inputs | h], h = sum_m state ----------------
__global__ void build_fused(const float* __restrict__ inputs, const float* __restrict__ state,
                            bf16* __restrict__ fused, bf16* __restrict__ reset) {
  int idx = blockIdx.x * blockDim.x + threadIdx.x;  // b*512 + u
  int b = idx >> 9, u = idx & 511;
  float x = inputs[(size_t)b * 512 + u];
  bf16 xb = __float2bfloat16(x);
  fused[(size_t)b * 1024 + u] = xb;
  reset[(size_t)b * 1024 + u] = xb;
  const float* sp = state + (size_t)b * 4096 + u * 8;
  float s[8];
  *(float4*)(s)     = *(const float4*)(sp);
  *(float4*)(s + 4) = *(const float4*)(sp + 4);
  float h = 0.f;
#pragma unroll
  for (int m = 0; m < 8; ++m) h += s[m];
  fused[(size_t)b * 1024 + 512 + u] = __float2bfloat16(h);
}

// ============ 8-phase 256x256 GEMM over permuted-col weights, fused CTGRU epilogue ============
// EPI 0: softmax_r + q_input -> reset[:,512+u] (bf16).  EPI 1: ski softmax + finalize -> out.
template <int EPI>
__global__ __launch_bounds__(512, 2) void gemm_fused(const bf16* __restrict__ A,
                                                     const bf16* __restrict__ Bt,
                                                     const float* __restrict__ bias,
                                                     const float* __restrict__ state,
                                                     const bf16* __restrict__ qk,
                                                     bf16* __restrict__ dreset,
                                                     float* __restrict__ dout) {
  __shared__ char smem[131072];
  const int tid = threadIdx.x;
  const int wid = tid >> 6, lane = tid & 63;
  const int g = lane >> 4, r = lane & 15;
  const int wr = wid >> 2, wc = wid & 3;  // 2 x 4 wave grid
  // grid: 256 blocks = 16 row-tiles x 16 col-tiles; XCD-bijective swizzle
  const int bid = blockIdx.x;
  const int xcd = bid & 7;
  const int n = bid >> 3;              // 32 per XCD
  const int bx = xcd * 2 + (n & 1);    // [0,16)
  const int by = n >> 1;               // [0,16)
  const int bm = by * 256;
  const int bn = bx * 256;

#define STAGE(op, h, tt) do {                                                          \
    const bf16* gbase_ = (op) ? Bt : A;                                                \
    const int rb_ = ((op) ? bn : bm) + (h) * 128;                                      \
    char* lb_ = smem + ((tt) & 1) * 65536 + (op) * 32768 + (h) * 16384;                \
    _Pragma("unroll")                                                                  \
    for (int j_ = 0; j_ < 2; ++j_) {                                                   \
      const int rowin_ = j_ * 64 + wid * 8;                                            \
      const int rowt_ = (h) * 128 + rowin_ + (lane >> 3);                              \
      const int slot_ = (lane & 7) ^ (rowt_ & 7);                                      \
      const bf16* src_ = gbase_ + (size_t)(rb_ + rowin_ + (lane >> 3)) * 1024          \
                         + (tt) * 64 + slot_ * 8;                                      \
      __builtin_amdgcn_global_load_lds((AS1 const void*)src_,                          \
                                       (AS3 void*)(lb_ + rowin_ * 128), 16, 0, 0);     \
    }                                                                                  \
  } while (0)

#define GATE() do {                                                                    \
    asm volatile("s_waitcnt vmcnt(6)" ::: "memory");                                   \
    __builtin_amdgcn_s_barrier();                                                      \
    asm volatile("" ::: "memory");                                                     \
  } while (0)

#define LDA(AH) do {                                                                   \
    _Pragma("unroll")                                                                  \
    for (int mi_ = 0; mi_ < 4; ++mi_) {                                                \
      const int rowt_ = (AH) * 128 + wr * 64 + mi_ * 16 + r;                           \
      _Pragma("unroll")                                                                \
      for (int ks_ = 0; ks_ < 2; ++ks_) {                                              \
        const int slot_ = (ks_ * 4 + g) ^ (rowt_ & 7);                                 \
        aF[mi_][ks_] = *(const short8*)(smem + bufoff + rowt_ * 128 + slot_ * 16);     \
      }                                                                                \
    }                                                                                  \
  } while (0)

#define LDB(DST, BH) do {                                                              \
    _Pragma("unroll")                                                                  \
    for (int ni_ = 0; ni_ < 2; ++ni_) {                                                \
      const int rowt_ = (BH) * 128 + wc * 32 + ni_ * 16 + r;                           \
      _Pragma("unroll")                                                                \
      for (int ks_ = 0; ks_ < 2; ++ks_) {                                              \
        const int slot_ = (ks_ * 4 + g) ^ (rowt_ & 7);                                 \
        DST[ni_][ks_] =                                                                \
            *(const short8*)(smem + bufoff + 32768 + rowt_ * 128 + slot_ * 16);        \
      }                                                                                \
    }                                                                                  \
  } while (0)

#define MM(AH, BH, BF) do {                                                            \
    __builtin_amdgcn_s_setprio(1);                                                     \
    _Pragma("unroll")                                                                  \
    for (int mi_ = 0; mi_ < 4; ++mi_)                                                  \
      _Pragma("unroll")                                                                \
      for (int ni_ = 0; ni_ < 2; ++ni_)                                                \
        _Pragma("unroll")                                                              \
        for (int ks_ = 0; ks_ < 2; ++ks_)                                              \
          acc[AH][mi_][BH][ni_] = __builtin_amdgcn_mfma_f32_16x16x32_bf16(             \
              aF[mi_][ks_], BF[ni_][ks_], acc[AH][mi_][BH][ni_], 0, 0, 0);             \
    __builtin_amdgcn_s_setprio(0);                                                     \
  } while (0)

  floatx4 acc[2][4][2][2] = {};
  short8 aF[4][2], bF0[2][2], bF1[2][2];

  STAGE(0, 0, 0);
  STAGE(1, 0, 0);
  STAGE(1, 1, 0);
  STAGE(0, 1, 0);

  for (int t = 0; t < 16; ++t) {
    const int bufoff = (t & 1) * 65536;
    const int tn = (t + 1) & 15;
    STAGE(0, 0, tn);
    GATE();
    LDA(0);
    LDB(bF0, 0);
    MM(0, 0, bF0);
    STAGE(1, 0, tn);
    GATE();
    LDB(bF1, 1);
    MM(0, 1, bF1);
    STAGE(1, 1, tn);
    GATE();
    LDA(1);
    MM(1, 0, bF0);
    STAGE(0, 1, tn);
    GATE();
    MM(1, 1, bF1);
  }

  asm volatile("s_waitcnt vmcnt(0)" ::: "memory");

  // ---------------- fused epilogue ----------------
  // physical col c = bh*128 + wc*32 + ni*16 + r ; u = bn/8 + wc*8 + (r&7) ;
  // m = bh*4 + ni*2 + parity, parity of own values = p = r>>3 (partner lane r^8 holds 1-p).
  const int p = r >> 3;
  const int u = (bn >> 3) + wc * 8 + (r & 7);

  float bv[8];
  *(float4*)(bv)     = *(const float4*)(bias + u * 8);
  *(float4*)(bv + 4) = *(const float4*)(bias + u * 8 + 4);

  float dec8[8];
  if (EPI == 1) {
    dec8[0] = 0.f;
#pragma unroll
    for (int m = 1; m < 8; ++m) dec8[m] = expf(-1.f / (m * LN_TAU_STEP));
  }

#pragma unroll
  for (int ah = 0; ah < 2; ++ah) {
    // this lane finalizes rows of half ah only when ah == p (partner does the other half),
    // but the exchange is symmetric: send own acc of half (1-p), receive partner's for half p.
#pragma unroll
    for (int mi = 0; mi < 4; ++mi) {
      float recv[2][2][4];
#pragma unroll
      for (int bh = 0; bh < 2; ++bh)
#pragma unroll
        for (int ni = 0; ni < 2; ++ni)
#pragma unroll
          for (int j = 0; j < 4; ++j) {
            float t = p ? acc[0][mi][bh][ni][j] : acc[1][mi][bh][ni][j];  // half 1-p
            recv[bh][ni][j] = __shfl_xor(t, 8);
          }
      if (ah == 0 ? (p == 0) : (p == 1)) {
#pragma unroll
        for (int j = 0; j < 4; ++j) {
          const int row = bm + p * 128 + wr * 64 + mi * 16 + g * 4 + j;
          float v[8];
#pragma unroll
          for (int bh = 0; bh < 2; ++bh)
#pragma unroll
            for (int ni = 0; ni < 2; ++ni) {
              const int k2 = bh * 4 + ni * 2;
              float own = p ? acc[1][mi][bh][ni][j] : acc[0][mi][bh][ni][j];  // half p
              float rcv = recv[bh][ni][j];
              float even = p ? rcv : own;   // m = k2
              float odd  = p ? own : rcv;   // m = k2+1
              v[k2]     = even + bv[k2];
              v[k2 + 1] = odd + bv[k2 + 1];
            }
          float lg[8], mx = -1e30f;
#pragma unroll
          for (int m = 0; m < 8; ++m) {
            float d = v[m] - m * LN_TAU_STEP;
            lg[m] = -d * d;
            mx = fmaxf(mx, lg[m]);
          }
          float st[8];
          const float* sp = state + (size_t)row * 4096 + u * 8;
          *(float4*)(st)     = *(const float4*)(sp);
          *(float4*)(st + 4) = *(const float4*)(sp + 4);
          float e[8], den = 0.f;
#pragma unroll
          for (int m = 0; m < 8; ++m) {
            e[m] = expf(lg[m] - mx);
            den += e[m];
          }
          if (EPI == 0) {
            float q = 0.f;
#pragma unroll
            for (int m = 0; m < 8; ++m) q += e[m] * st[m];
            dreset[(size_t)row * 1024 + 512 + u] = __float2bfloat16(q / den);
          } else {
            const float qv = __bfloat162float(qk[(size_t)row * 512 + u]);
            const float inv = 1.f / den;
            float res[8], hn = 0.f;
#pragma unroll
            for (int m = 0; m < 8; ++m) {
              float s = e[m] * inv;
              float val = ((1.f - s) * st[m] + s * qv) * dec8[m];
              res[m] = val;
              hn += val;
            }
            dout[(size_t)row * 512 + u] = hn;
            float* op = dout + (size_t)4096 * 512 + (size_t)row * 4096 + u * 8;
            *(float4*)(op)     = *(const float4*)(res);
            *(float4*)(op + 4) = *(const float4*)(res + 4);
          }
        }
      }
    }
  }
#undef STAGE
#undef GATE
#undef LDA
#undef LDB
#undef MM
}

// ================= small GEMM (reset @ Wq), 64x64 tiles, tanh, bf16 out =================
__global__ __launch_bounds__(256) void gemm_q(const bf16* __restrict__ A,
                                              const bf16* __restrict__ Bt,
                                              const float* __restrict__ bias,
                                              bf16* __restrict__ C) {
  __shared__ bf16 lA[64 * 32];
  __shared__ bf16 lB[64 * 32];
  const int tid = threadIdx.x;
  const int wave = tid >> 6;
  const int lane = tid & 63;
  const int g = lane >> 4;
  const int r = lane & 15;
  const int wr = wave >> 1, wc = wave & 1;
  const int bm = blockIdx.y * 64;
  const int bn = blockIdx.x * 64;

  floatx4 acc[2][2] = {};
  const int srow = wave * 16 + (lane >> 2);
  const int scol = (lane & 3) * 8;

  for (int kt = 0; kt < K_DIM; kt += 32) {
    const bf16* ga = A + (size_t)(bm + srow) * K_DIM + kt + scol;
    __builtin_amdgcn_global_load_lds((AS1 const void*)(ga),
                                     (AS3 void*)(lA + (wave * 16) * 32), 16, 0, 0);
    const bf16* gb = Bt + (size_t)(bn + srow) * K_DIM + kt + scol;
    __builtin_amdgcn_global_load_lds((AS1 const void*)(gb),
                                     (AS3 void*)(lB + (wave * 16) * 32), 16, 0, 0);
    __syncthreads();
    short8 aF[2], bF[2];
#pragma unroll
    for (int mi = 0; mi < 2; ++mi)
      aF[mi] = *(const short8*)(lA + (wr * 32 + mi * 16 + r) * 32 + g * 8);
#pragma unroll
    for (int ni = 0; ni < 2; ++ni)
      bF[ni] = *(const short8*)(lB + (wc * 32 + ni * 16 + r) * 32 + g * 8);
#pragma unroll
    for (int mi = 0; mi < 2; ++mi)
#pragma unroll
      for (int ni = 0; ni < 2; ++ni)
        acc[mi][ni] =
            __builtin_amdgcn_mfma_f32_16x16x32_bf16(aF[mi], bF[ni], acc[mi][ni], 0, 0, 0);
    __syncthreads();
  }

#pragma unroll
  for (int mi = 0; mi < 2; ++mi) {
#pragma unroll
    for (int ni = 0; ni < 2; ++ni) {
      const int col = bn + wc * 32 + ni * 16 + r;
      const float bv = bias[col];
#pragma unroll
      for (int j = 0; j < 4; ++j) {
        const int row = bm + wr * 32 + mi * 16 + g * 4 + j;
        C[(size_t)row * 512 + col] = __float2bfloat16(tanhf(acc[mi][ni][j] + bv));
      }
    }
  }
}

extern "C" void kernel_launch(void* const* d_in, const int* in_sizes, int n_in, void* d_out,
                              int out_size, void* d_ws, size_t ws_size, hipStream_t stream) {
  const float* inputs = (const float*)d_in[0];
  const float* state  = (const float*)d_in[1];
  const float* Wr     = (const float*)d_in[2];
  const float* br     = (const float*)d_in[3];
  const float* Ws     = (const float*)d_in[4];
  const float* bs     = (const float*)d_in[5];
  const float* Wq     = (const float*)d_in[6];
  const float* bq     = (const float*)d_in[7];
  float* out = (float*)d_out;

  char* ws = (char*)d_ws;
  bf16* Wt    = (bf16*)(ws);                       // 16 MiB [2][4096 perm rows][1024]
  bf16* Wqt   = (bf16*)(ws + (16ull << 20));       // 1 MiB  [512][1024]
  bf16* fused = (bf16*)(ws + (17ull << 20));       // 8 MiB  [4096][1024]
  bf16* reset = (bf16*)(ws + (25ull << 20));       // 8 MiB
  bf16* qk    = (bf16*)(ws + (33ull << 20));       // 4 MiB  [4096][512]

  dim3 tb(32, 8);
  transpose_rs<<<dim3(128, 32, 2), tb, 0, stream>>>(Wr, Ws, Wt);
  transpose_q<<<dim3(16, 32), tb, 0, stream>>>(Wq, Wqt);
  build_fused<<<8192, 256, 0, stream>>>(inputs, state, fused, reset);
  gemm_fused<0><<<256, 512, 0, stream>>>(fused, Wt, br, state, nullptr, reset, nullptr);
  gemm_q<<<dim3(8, 64), 256, 0, stream>>>(reset, Wqt, bq, qk);
  gemm_fused<1><<<256, 512, 0, stream>>>(fused, Wt + (size_t)4096 * 1024, bs, state, qk,
                                         nullptr, out);
}

// Round 7
// 157.827 us; speedup vs baseline: 1.4723x; 1.4723x over previous
//
#include <hip/hip_runtime.h>
#include <hip/hip_bf16.h>

typedef __hip_bfloat16 bf16;
typedef __attribute__((ext_vector_type(8))) short short8;
typedef __attribute__((ext_vector_type(4))) float floatx4;

#define AS1 __attribute__((address_space(1)))
#define AS3 __attribute__((address_space(3)))

#define K_DIM 1024
#define LN_TAU_STEP 1.15129254649702295f

__device__ __forceinline__ float bfbits2f(unsigned short v) {
  unsigned int u = ((unsigned int)v) << 16;
  return __builtin_bit_cast(float, u);
}

// ---------------- transpose f32 [K][N=4096] -> bf16 [N][K], z selects Wr/Ws ----------------
__global__ void transpose_rs(const float* __restrict__ Wr, const float* __restrict__ Ws,
                             bf16* __restrict__ dst) {
  __shared__ float tile[32][33];
  const float* src = blockIdx.z ? Ws : Wr;
  bf16* d = dst + (size_t)blockIdx.z * 4096 * 1024;
  int n0 = blockIdx.x * 32, k0 = blockIdx.y * 32;
  int tx = threadIdx.x, ty = threadIdx.y;
#pragma unroll
  for (int i = 0; i < 32; i += 8)
    tile[ty + i][tx] = src[(size_t)(k0 + ty + i) * 4096 + n0 + tx];
  __syncthreads();
#pragma unroll
  for (int i = 0; i < 32; i += 8)
    d[(size_t)(n0 + ty + i) * 1024 + k0 + tx] = __float2bfloat16(tile[tx][ty + i]);
}

// ---------------- transpose f32 [1024][512] -> bf16 [512][1024] ----------------
__global__ void transpose_q(const float* __restrict__ src, bf16* __restrict__ dst) {
  __shared__ float tile[32][33];
  int n0 = blockIdx.x * 32, k0 = blockIdx.y * 32;
  int tx = threadIdx.x, ty = threadIdx.y;
#pragma unroll
  for (int i = 0; i < 32; i += 8)
    tile[ty + i][tx] = src[(size_t)(k0 + ty + i) * 512 + n0 + tx];
  __syncthreads();
#pragma unroll
  for (int i = 0; i < 32; i += 8)
    dst[(size_t)(n0 + ty + i) * 1024 + k0 + tx] = __float2bfloat16(tile[tx][ty + i]);
}

// ---------------- build fused = [inputs | h], h = sum_m state ----------------
__global__ void build_fused(const float* __restrict__ inputs, const float* __restrict__ state,
                            bf16* __restrict__ fused, bf16* __restrict__ reset) {
  int idx = blockIdx.x * blockDim.x + threadIdx.x;  // b*512 + u
  int b = idx >> 9, u = idx & 511;
  float x = inputs[(size_t)b * 512 + u];
  bf16 xb = __float2bfloat16(x);
  fused[(size_t)b * 1024 + u] = xb;
  reset[(size_t)b * 1024 + u] = xb;
  const float* sp = state + (size_t)b * 4096 + u * 8;
  float s[8];
  *(float4*)(s)     = *(const float4*)(sp);
  *(float4*)(s + 4) = *(const float4*)(sp + 4);
  float h = 0.f;
#pragma unroll
  for (int m = 0; m < 8; ++m) h += s[m];
  fused[(size_t)b * 1024 + 512 + u] = __float2bfloat16(h);
}

// ============ 8-phase 256x256 GEMM: C[4096][8192] = fused @ [Wr|Ws] + bias, bf16 out ============
// BK=64, 8 waves (2x4). Per-phase ds_reads issued BEFORE the gate (barrier wait absorbs LDS
// latency); vmcnt tightened to 4 at P0/P1 so pre-gate reads are covered (deadline audit in
// journal). Stage order per iter (next tile): A0,B0,B1,A1.
__global__ __launch_bounds__(512, 2) void gemm_rs_8p(const bf16* __restrict__ A,
                                                     const bf16* __restrict__ Bt,
                                                     const float* __restrict__ br,
                                                     const float* __restrict__ bs,
                                                     bf16* __restrict__ C) {
  __shared__ char smem[131072];  // [buf:2][op:2][256 rows][128B (8 swizzled 16B slots)]
  const int tid = threadIdx.x;
  const int wid = tid >> 6, lane = tid & 63;
  const int g = lane >> 4, r = lane & 15;
  const int wr = wid >> 2, wc = wid & 3;  // 2 x 4 wave grid
  const int bid = blockIdx.x;
  const int xcd = bid & 7;
  const int n = bid >> 3;           // 64 blocks per XCD
  const int sg = n >> 4, l2 = n & 15;
  const int bx = xcd * 4 + (l2 & 3);   // [0,32)
  const int by = sg * 4 + (l2 >> 2);   // [0,16)
  const int bm = by * 256;
  const int bn = bx * 256;

#define STAGE(op, h, tt) do {                                                          \
    const bf16* gbase_ = (op) ? Bt : A;                                                \
    const int rb_ = ((op) ? bn : bm) + (h) * 128;                                      \
    char* lb_ = smem + ((tt) & 1) * 65536 + (op) * 32768 + (h) * 16384;                \
    _Pragma("unroll")                                                                  \
    for (int j_ = 0; j_ < 2; ++j_) {                                                   \
      const int rowin_ = j_ * 64 + wid * 8;                                            \
      const int rowt_ = (h) * 128 + rowin_ + (lane >> 3);                              \
      const int slot_ = (lane & 7) ^ (rowt_ & 7);                                      \
      const bf16* src_ = gbase_ + (size_t)(rb_ + rowin_ + (lane >> 3)) * 1024          \
                         + (tt) * 64 + slot_ * 8;                                      \
      __builtin_amdgcn_global_load_lds((AS1 const void*)src_,                          \
                                       (AS3 void*)(lb_ + rowin_ * 128), 16, 0, 0);     \
    }                                                                                  \
  } while (0)

#define GATE(N) do {                                                                   \
    asm volatile("s_waitcnt vmcnt(" #N ")" ::: "memory");                              \
    __builtin_amdgcn_s_barrier();                                                      \
    asm volatile("" ::: "memory");                                                     \
  } while (0)

#define LDA(DST, AH) do {                                                              \
    _Pragma("unroll")                                                                  \
    for (int mi_ = 0; mi_ < 4; ++mi_) {                                                \
      const int rowt_ = (AH) * 128 + wr * 64 + mi_ * 16 + r;                           \
      _Pragma("unroll")                                                                \
      for (int ks_ = 0; ks_ < 2; ++ks_) {                                              \
        const int slot_ = (ks_ * 4 + g) ^ (rowt_ & 7);                                 \
        DST[mi_][ks_] = *(const short8*)(smem + bufoff + rowt_ * 128 + slot_ * 16);    \
      }                                                                                \
    }                                                                                  \
  } while (0)

#define LDB(DST, BH) do {                                                              \
    _Pragma("unroll")                                                                  \
    for (int ni_ = 0; ni_ < 2; ++ni_) {                                                \
      const int rowt_ = (BH) * 128 + wc * 32 + ni_ * 16 + r;                           \
      _Pragma("unroll")                                                                \
      for (int ks_ = 0; ks_ < 2; ++ks_) {                                              \
        const int slot_ = (ks_ * 4 + g) ^ (rowt_ & 7);                                 \
        DST[ni_][ks_] =                                                                \
            *(const short8*)(smem + bufoff + 32768 + rowt_ * 128 + slot_ * 16);        \
      }                                                                                \
    }                                                                                  \
  } while (0)

#define MM(AH, BH, BF) do {                                                            \
    __builtin_amdgcn_s_setprio(1);                                                     \
    _Pragma("unroll")                                                                  \
    for (int mi_ = 0; mi_ < 4; ++mi_)                                                  \
      _Pragma("unroll")                                                                \
      for (int ni_ = 0; ni_ < 2; ++ni_)                                                \
        _Pragma("unroll")                                                              \
        for (int ks_ = 0; ks_ < 2; ++ks_)                                              \
          acc[AH][mi_][BH][ni_] = __builtin_amdgcn_mfma_f32_16x16x32_bf16(             \
              aF##AH[mi_][ks_], BF[ni_][ks_], acc[AH][mi_][BH][ni_], 0, 0, 0);         \
    __builtin_amdgcn_s_setprio(0);                                                     \
  } while (0)

  floatx4 acc[2][4][2][2] = {};
  short8 aF0[4][2], aF1[4][2], bF0[2][2], bF1[2][2];

  // prologue: stage tile 0 (A0,B0,B1,A1); first P0 gate covers A0/B0/B1 visibility
  STAGE(0, 0, 0);
  STAGE(1, 0, 0);
  STAGE(1, 1, 0);
  STAGE(0, 1, 0);

  for (int t = 0; t < 16; ++t) {
    const int bufoff = (t & 1) * 65536;
    const int tn = (t + 1) & 15;  // t=15 redundantly re-stages tile 0 (uniform counts)
    // P0: gate(vmcnt4) guarantees A0,B0,B1 of tile t landed. JIT-read A0,B0 frags.
    STAGE(0, 0, tn);
    GATE(4);
    LDA(aF0, 0);
    LDB(bF0, 0);
    MM(0, 0, bF0);
    // P1: pre-read bF1 (B1 visible since gate P0); gate(vmcnt4) guarantees A1 landed.
    STAGE(1, 0, tn);
    LDB(bF1, 1);
    GATE(4);
    MM(0, 1, bF1);
    // P2: pre-read aF1 (A1 visible since gate P1).
    STAGE(1, 1, tn);
    LDA(aF1, 1);
    GATE(6);
    MM(1, 0, bF0);
    // P3: all frags resident; gate(vmcnt6) guarantees A0 of tile t+1 landed for next P0.
    STAGE(0, 1, tn);
    GATE(6);
    MM(1, 1, bF1);
  }

  asm volatile("s_waitcnt vmcnt(0)" ::: "memory");  // drain redundant stages before exit

  const float* bias = (bn < 4096) ? br : bs;
#pragma unroll
  for (int ah = 0; ah < 2; ++ah)
#pragma unroll
    for (int mi = 0; mi < 4; ++mi)
#pragma unroll
      for (int bh = 0; bh < 2; ++bh)
#pragma unroll
        for (int ni = 0; ni < 2; ++ni) {
          const int col = bn + bh * 128 + wc * 32 + ni * 16 + r;
          const float bv = bias[col & 4095];
#pragma unroll
          for (int j = 0; j < 4; ++j) {
            const int row = bm + ah * 128 + wr * 64 + mi * 16 + g * 4 + j;
            C[(size_t)row * 8192 + col] = __float2bfloat16(acc[ah][mi][bh][ni][j] + bv);
          }
        }
#undef STAGE
#undef GATE
#undef LDA
#undef LDB
#undef MM
}

// ---------------- softmax over M of -(r - ln_tau)^2, q_input = sum(p * h_hat) ----------------
__global__ void softmax_r(const bf16* __restrict__ C, const float* __restrict__ state,
                          bf16* __restrict__ reset) {
  int idx = blockIdx.x * blockDim.x + threadIdx.x;  // b*512 + u
  int b = idx >> 9, u = idx & 511;
  short8 rv = *(const short8*)(C + (size_t)b * 8192 + u * 8);
  const float* sp = state + (size_t)b * 4096 + u * 8;
  float ss[8];
  *(float4*)(ss)     = *(const float4*)(sp);
  *(float4*)(ss + 4) = *(const float4*)(sp + 4);
  float lg[8], mx = -1e30f;
#pragma unroll
  for (int m = 0; m < 8; ++m) {
    float d = bfbits2f((unsigned short)rv[m]) - m * LN_TAU_STEP;
    lg[m] = -d * d;
    mx = fmaxf(mx, lg[m]);
  }
  float sum = 0.f, q = 0.f;
#pragma unroll
  for (int m = 0; m < 8; ++m) {
    float e = expf(lg[m] - mx);
    sum += e;
    q += e * ss[m];
  }
  reset[(size_t)b * 1024 + 512 + u] = __float2bfloat16(q / sum);
}

// ---------------- final: ski softmax, h_hat_next, h_next ----------------
__global__ void finalize(const bf16* __restrict__ C, const float* __restrict__ state,
                         const bf16* __restrict__ qk, float* __restrict__ out) {
  int idx = blockIdx.x * blockDim.x + threadIdx.x;  // b*512 + u
  int b = idx >> 9, u = idx & 511;
  short8 sv = *(const short8*)(C + (size_t)b * 8192 + 4096 + u * 8);
  const float* hp = state + (size_t)b * 4096 + u * 8;
  float qv = __bfloat162float(qk[(size_t)b * 512 + u]);
  float hh[8];
  *(float4*)(hh)     = *(const float4*)(hp);
  *(float4*)(hh + 4) = *(const float4*)(hp + 4);
  float lg[8], mx = -1e30f;
#pragma unroll
  for (int m = 0; m < 8; ++m) {
    float d = bfbits2f((unsigned short)sv[m]) - m * LN_TAU_STEP;
    lg[m] = -d * d;
    mx = fmaxf(mx, lg[m]);
  }
  float sum = 0.f, e[8];
#pragma unroll
  for (int m = 0; m < 8; ++m) {
    e[m] = expf(lg[m] - mx);
    sum += e[m];
  }
  float inv = 1.f / sum;
  float hn = 0.f, res[8];
#pragma unroll
  for (int m = 0; m < 8; ++m) {
    float t = m * LN_TAU_STEP;
    float dec = (m == 0) ? 0.f : expf(-1.f / t);
    float s = e[m] * inv;
    float v = ((1.f - s) * hh[m] + s * qv) * dec;
    res[m] = v;
    hn += v;
  }
  out[(size_t)b * 512 + u] = hn;
  float* op = out + (size_t)4096 * 512 + (size_t)b * 4096 + u * 8;
  *(float4*)(op)     = *(const float4*)(res);
  *(float4*)(op + 4) = *(const float4*)(res + 4);
}

// ================= small GEMM (reset @ Wq), 64x64 tiles, tanh, bf16 out =================
__global__ __launch_bounds__(256) void gemm_q(const bf16* __restrict__ A,
                                              const bf16* __restrict__ Bt,
                                              const float* __restrict__ bias,
                                              bf16* __restrict__ C) {
  __shared__ bf16 lA[64 * 32];
  __shared__ bf16 lB[64 * 32];
  const int tid = threadIdx.x;
  const int wave = tid >> 6;
  const int lane = tid & 63;
  const int g = lane >> 4;
  const int r = lane & 15;
  const int wr = wave >> 1, wc = wave & 1;
  const int bm = blockIdx.y * 64;
  const int bn = blockIdx.x * 64;

  floatx4 acc[2][2] = {};
  const int srow = wave * 16 + (lane >> 2);
  const int scol = (lane & 3) * 8;

  for (int kt = 0; kt < K_DIM; kt += 32) {
    const bf16* ga = A + (size_t)(bm + srow) * K_DIM + kt + scol;
    __builtin_amdgcn_global_load_lds((AS1 const void*)(ga),
                                     (AS3 void*)(lA + (wave * 16) * 32), 16, 0, 0);
    const bf16* gb = Bt + (size_t)(bn + srow) * K_DIM + kt + scol;
    __builtin_amdgcn_global_load_lds((AS1 const void*)(gb),
                                     (AS3 void*)(lB + (wave * 16) * 32), 16, 0, 0);
    __syncthreads();
    short8 aF[2], bF[2];
#pragma unroll
    for (int mi = 0; mi < 2; ++mi)
      aF[mi] = *(const short8*)(lA + (wr * 32 + mi * 16 + r) * 32 + g * 8);
#pragma unroll
    for (int ni = 0; ni < 2; ++ni)
      bF[ni] = *(const short8*)(lB + (wc * 32 + ni * 16 + r) * 32 + g * 8);
#pragma unroll
    for (int mi = 0; mi < 2; ++mi)
#pragma unroll
      for (int ni = 0; ni < 2; ++ni)
        acc[mi][ni] =
            __builtin_amdgcn_mfma_f32_16x16x32_bf16(aF[mi], bF[ni], acc[mi][ni], 0, 0, 0);
    __syncthreads();
  }

#pragma unroll
  for (int mi = 0; mi < 2; ++mi) {
#pragma unroll
    for (int ni = 0; ni < 2; ++ni) {
      const int col = bn + wc * 32 + ni * 16 + r;
      const float bv = bias[col];
#pragma unroll
      for (int j = 0; j < 4; ++j) {
        const int row = bm + wr * 32 + mi * 16 + g * 4 + j;
        C[(size_t)row * 512 + col] = __float2bfloat16(tanhf(acc[mi][ni][j] + bv));
      }
    }
  }
}

extern "C" void kernel_launch(void* const* d_in, const int* in_sizes, int n_in, void* d_out,
                              int out_size, void* d_ws, size_t ws_size, hipStream_t stream) {
  const float* inputs = (const float*)d_in[0];
  const float* state  = (const float*)d_in[1];
  const float* Wr     = (const float*)d_in[2];
  const float* br     = (const float*)d_in[3];
  const float* Ws     = (const float*)d_in[4];
  const float* bs     = (const float*)d_in[5];
  const float* Wq     = (const float*)d_in[6];
  const float* bq     = (const float*)d_in[7];
  float* out = (float*)d_out;

  char* ws = (char*)d_ws;
  bf16* Wt    = (bf16*)(ws);                       // 16 MiB [8192][1024] = [Wr^T ; Ws^T]
  bf16* Wqt   = (bf16*)(ws + (16ull << 20));       // 1 MiB  [512][1024]
  bf16* fused = (bf16*)(ws + (17ull << 20));       // 8 MiB  [4096][1024]
  bf16* reset = (bf16*)(ws + (25ull << 20));       // 8 MiB
  bf16* qk    = (bf16*)(ws + (33ull << 20));       // 4 MiB  [4096][512]
  bf16* Cbuf  = (bf16*)(ws + (41ull << 20));       // 64 MiB [4096][8192] bf16

  dim3 tb(32, 8);
  transpose_rs<<<dim3(128, 32, 2), tb, 0, stream>>>(Wr, Ws, Wt);
  transpose_q<<<dim3(16, 32), tb, 0, stream>>>(Wq, Wqt);
  build_fused<<<8192, 256, 0, stream>>>(inputs, state, fused, reset);
  gemm_rs_8p<<<512, 512, 0, stream>>>(fused, Wt, br, bs, Cbuf);
  softmax_r<<<8192, 256, 0, stream>>>(Cbuf, state, reset);
  gemm_q<<<dim3(8, 64), 256, 0, stream>>>(reset, Wqt, bq, qk);
  finalize<<<8192, 256, 0, stream>>>(Cbuf, state, qk, out);
}